// Round 1
// baseline (3704.501 us; speedup 1.0000x reference)
//
#include <hip/hip_runtime.h>
#include <math.h>

#define NN 8192
#define NH 1024

typedef __bf16 bf16x8 __attribute__((ext_vector_type(8)));
typedef float floatx4 __attribute__((ext_vector_type(4)));

__device__ __forceinline__ unsigned short f2bf(float f) {
  unsigned int u = __float_as_uint(f);
  u += 0x7fffu + ((u >> 16) & 1u);
  return (unsigned short)(u >> 16);
}

__device__ __forceinline__ void async16(const void* g, void* l) {
  __builtin_amdgcn_global_load_lds(
      (__attribute__((address_space(1))) void*)(g),
      (__attribute__((address_space(3))) void*)(l), 16, 0, 0);
}

// ---------------- GEMM: C = A(MxK bf16,row-major) * Bt(NxK bf16)^T, N=1024 ----
// EPI 0: sup = 0.3*C + 0.7*aux(h0);     write outf=sup_f32, outb=sup_bf16
// EPI 1: o = th*C + (1-th)*aux(sup) + outf(h_prev); relu; write outf,outb
// EPI 2: same as 1 but ELU
template<int EPI>
__global__ __launch_bounds__(256)
void gemm_bt(const unsigned short* __restrict__ A,
             const unsigned short* __restrict__ Bt,
             int K,
             const float* __restrict__ aux,
             float* outf,
             unsigned short* __restrict__ outb,
             float theta)
{
  __shared__ __align__(16) unsigned short lA[128 * 32];
  __shared__ __align__(16) unsigned short lB[128 * 32];
  const int tid  = threadIdx.x;
  const int lane = tid & 63;
  const int wave = tid >> 6;
  const long tileM = (long)blockIdx.y * 128;
  const long tileN = (long)blockIdx.x * 128;
  const int wm = (wave & 1) * 64;
  const int wn = (wave >> 1) * 64;

  // staging: each wave covers two contiguous 1KB LDS chunks (16 rows x 32 bf16)
  const int srow = lane >> 2;
  const int scol = (lane & 3) * 8;
  const int r0 = wave * 16 + srow;
  const int r1 = 64 + wave * 16 + srow;

  const unsigned short* gA0 = A + (tileM + r0) * (long)K + scol;
  const unsigned short* gA1 = A + (tileM + r1) * (long)K + scol;
  const unsigned short* gB0 = Bt + (tileN + r0) * (long)K + scol;
  const unsigned short* gB1 = Bt + (tileN + r1) * (long)K + scol;
  unsigned short* lA0 = &lA[r0 * 32 + scol];
  unsigned short* lA1 = &lA[r1 * 32 + scol];
  unsigned short* lB0 = &lB[r0 * 32 + scol];
  unsigned short* lB1 = &lB[r1 * 32 + scol];

  const int fr = lane & 15;
  const int q8 = (lane >> 4) * 8;

  floatx4 zero4 = {0.f, 0.f, 0.f, 0.f};
  floatx4 acc[4][4];
#pragma unroll
  for (int i = 0; i < 4; ++i)
#pragma unroll
    for (int j = 0; j < 4; ++j) acc[i][j] = zero4;

  const int nkt = K >> 5;
  for (int kt = 0; kt < nkt; ++kt) {
    const int k0 = kt << 5;
    async16(gA0 + k0, lA0);
    async16(gA1 + k0, lA1);
    async16(gB0 + k0, lB0);
    async16(gB1 + k0, lB1);
    __syncthreads();
    bf16x8 af[4], bf[4];
#pragma unroll
    for (int i = 0; i < 4; ++i)
      af[i] = *(const bf16x8*)&lA[(wm + 16 * i + fr) * 32 + q8];
#pragma unroll
    for (int j = 0; j < 4; ++j)
      bf[j] = *(const bf16x8*)&lB[(wn + 16 * j + fr) * 32 + q8];
#pragma unroll
    for (int i = 0; i < 4; ++i)
#pragma unroll
      for (int j = 0; j < 4; ++j)
        acc[i][j] = __builtin_amdgcn_mfma_f32_16x16x32_bf16(af[i], bf[j], acc[i][j], 0, 0, 0);
    __syncthreads();
  }

  // epilogue: C/D layout col=lane&15, row=(lane>>4)*4+reg
  const int crow = (lane >> 4) * 4;
#pragma unroll
  for (int i = 0; i < 4; ++i) {
#pragma unroll
    for (int j = 0; j < 4; ++j) {
#pragma unroll
      for (int r = 0; r < 4; ++r) {
        long row = tileM + wm + 16 * i + crow + r;
        long col = tileN + wn + 16 * j + fr;
        long idx = row * NH + col;
        float v = acc[i][j][r];
        if (EPI == 0) {
          float s = 0.3f * v + 0.7f * aux[idx];
          outf[idx] = s;
          outb[idx] = f2bf(s);
        } else {
          float o = theta * v + (1.f - theta) * aux[idx] + outf[idx];
          o = (EPI == 1) ? fmaxf(o, 0.f) : (o > 0.f ? o : __expf(o) - 1.f);
          outf[idx] = o;
          outb[idx] = f2bf(o);
        }
      }
    }
  }
}

// ---------------- fp32 (R x C) -> bf16 transposed (C x R) ----------------
__global__ __launch_bounds__(256)
void transpose_f32_bf16(const float* __restrict__ src, unsigned short* __restrict__ dst,
                        int R, int C) {
  __shared__ float t[32][33];
  int tid = threadIdx.x;
  int tx = tid & 31, ty = tid >> 5;
  long r0 = (long)blockIdx.y * 32, c0 = (long)blockIdx.x * 32;
#pragma unroll
  for (int i = 0; i < 32; i += 8)
    t[ty + i][tx] = src[(r0 + ty + i) * C + c0 + tx];
  __syncthreads();
#pragma unroll
  for (int i = 0; i < 32; i += 8)
    dst[(c0 + ty + i) * R + r0 + tx] = f2bf(t[tx][ty + i]);
}

// ---------------- fp32 -> bf16 elementwise (dist) ----------------
__global__ __launch_bounds__(256)
void f32_to_bf16_vec(const float* __restrict__ s, unsigned short* __restrict__ d) {
  long i = (blockIdx.x * 256L + threadIdx.x) * 4;
  float4 v = *(const float4*)(s + i);
  *(ushort4*)(d + i) = make_ushort4(f2bf(v.x), f2bf(v.y), f2bf(v.z), f2bf(v.w));
}

// ---------------- h0 = relu(x @ fc_W + fc_b) ----------------
__global__ __launch_bounds__(256)
void fc_kernel(const float* __restrict__ x, const float* __restrict__ W,
               const float* __restrict__ b, float* __restrict__ h0f,
               float* __restrict__ hf) {
  __shared__ float xs[64];
  int row = blockIdx.x, tid = threadIdx.x;
  if (tid < 63) xs[tid] = x[row * 63 + tid];
  __syncthreads();
#pragma unroll
  for (int q = 0; q < 4; ++q) {
    int c = tid + q * 256;
    float s = b[c];
    for (int k = 0; k < 63; ++k) s += xs[k] * W[k * NH + c];
    s = fmaxf(s, 0.f);
    long idx = (long)row * NH + c;
    h0f[idx] = s;
    hf[idx] = s;
  }
}

// ---------------- va1 = gat_W @ a1, va2 = gat_W @ a2 ----------------
__global__ __launch_bounds__(256)
void wv_kernel(const float* __restrict__ W, const float* __restrict__ a,
               float* __restrict__ va1, float* __restrict__ va2) {
  int k = blockIdx.x, tid = threadIdx.x;
  float s1 = 0.f, s2 = 0.f;
  for (int n = tid; n < NH; n += 256) {
    float w = W[(long)k * NH + n];
    s1 += w * a[n];
    s2 += w * a[NH + n];
  }
#pragma unroll
  for (int o = 32; o; o >>= 1) { s1 += __shfl_down(s1, o); s2 += __shfl_down(s2, o); }
  __shared__ float r1[4], r2[4];
  int wave = tid >> 6;
  if ((tid & 63) == 0) { r1[wave] = s1; r2[wave] = s2; }
  __syncthreads();
  if (tid == 0) {
    va1[k] = r1[0] + r1[1] + r1[2] + r1[3];
    va2[k] = r2[0] + r2[1] + r2[2] + r2[3];
  }
}

// ---------------- f = h @ va1, g = h @ va2 ----------------
__global__ __launch_bounds__(256)
void fg_kernel(const float* __restrict__ h, const float* __restrict__ va1,
               const float* __restrict__ va2, float* __restrict__ fv,
               float* __restrict__ gv) {
  int row = blockIdx.x, tid = threadIdx.x;
  float s1 = 0.f, s2 = 0.f;
  for (int k = tid; k < NH; k += 256) {
    float v = h[(long)row * NH + k];
    s1 += v * va1[k];
    s2 += v * va2[k];
  }
#pragma unroll
  for (int o = 32; o; o >>= 1) { s1 += __shfl_down(s1, o); s2 += __shfl_down(s2, o); }
  __shared__ float r1[4], r2[4];
  int wave = tid >> 6;
  if ((tid & 63) == 0) { r1[wave] = s1; r2[wave] = s2; }
  __syncthreads();
  if (tid == 0) {
    fv[row] = r1[0] + r1[1] + r1[2] + r1[3];
    gv[row] = r2[0] + r2[1] + r2[2] + r2[3];
  }
}

// ---------------- attention pass 1: per-row max & denom ----------------
__global__ __launch_bounds__(256)
void attn_ml(const int* __restrict__ adj, const float* __restrict__ f,
             const float* __restrict__ g, float* __restrict__ Mr,
             float* __restrict__ Lr) {
  const int row = blockIdx.x, tid = threadIdx.x;
  const float fi = f[row];
  const int4* arow = (const int4*)(adj + (long)row * NN);
  float m = -3.0e38f, s = 0.f;
  for (int c = tid; c < NN / 4; c += 256) {
    int4 a = arow[c];
    float4 gg = *(const float4*)(g + c * 4);
#pragma unroll
    for (int t = 0; t < 4; ++t) {
      int av = (t == 0) ? a.x : (t == 1) ? a.y : (t == 2) ? a.z : a.w;
      float gvv = (t == 0) ? gg.x : (t == 1) ? gg.y : (t == 2) ? gg.z : gg.w;
      if (av > 0) {
        float e = fi + gvv;
        e = e > 0.f ? e : 0.2f * e;
        if (e > m) { s = s * __expf(m - e) + 1.f; m = e; }
        else s += __expf(e - m);
      }
    }
  }
#pragma unroll
  for (int o = 32; o; o >>= 1) {
    float m2 = __shfl_down(m, o), s2 = __shfl_down(s, o);
    float mn = fmaxf(m, m2);
    s = s * __expf(m - mn) + s2 * __expf(m2 - mn);
    m = mn;
  }
  __shared__ float ms[4], ss[4];
  int wave = tid >> 6;
  if ((tid & 63) == 0) { ms[wave] = m; ss[wave] = s; }
  __syncthreads();
  if (tid == 0) {
    float mm = ms[0], sv = ss[0];
    for (int w = 1; w < 4; ++w) {
      float mn = fmaxf(mm, ms[w]);
      sv = sv * __expf(mm - mn) + ss[w] * __expf(ms[w] - mn);
      mm = mn;
    }
    Mr[row] = mm;
    Lr[row] = sv;
  }
}

// ---------------- attention pass 2: P (bf16) ----------------
__global__ __launch_bounds__(256)
void attn_p(const int* __restrict__ adj, const float* __restrict__ f,
            const float* __restrict__ g, const float* __restrict__ Mr,
            const float* __restrict__ Lr, unsigned short* __restrict__ P) {
  long gid = blockIdx.x * 256L + threadIdx.x;
  int row = (int)(gid >> 11);
  int jc = (int)(gid & 2047) * 4;
  float fi = f[row], m = Mr[row], l = Lr[row];
  bool uni = !(l > 0.f);
  float inv = uni ? 0.f : 1.f / l;
  int4 a = *(const int4*)(adj + ((long)row << 13) + jc);
  float4 gg = *(const float4*)(g + jc);
  float p[4];
#pragma unroll
  for (int t = 0; t < 4; ++t) {
    int av = (t == 0) ? a.x : (t == 1) ? a.y : (t == 2) ? a.z : a.w;
    float gvv = (t == 0) ? gg.x : (t == 1) ? gg.y : (t == 2) ? gg.z : gg.w;
    float e = fi + gvv;
    e = e > 0.f ? e : 0.2f * e;
    float pv = (av > 0) ? __expf(e - m) * inv : 0.f;
    if (uni) pv = 1.f / (float)NN;
    p[t] = pv;
  }
  *(ushort4*)(P + ((long)row << 13) + jc) =
      make_ushort4(f2bf(p[0]), f2bf(p[1]), f2bf(p[2]), f2bf(p[3]));
}

// ---------------- classifier head: sigmoid(relu(h@W1+b1)@W3+b3) ----------------
__global__ __launch_bounds__(256)
void cls_kernel(const float* __restrict__ h, const float* __restrict__ W1,
                const float* __restrict__ b1, const float* __restrict__ W3,
                const float* __restrict__ b3, float* __restrict__ out) {
  __shared__ float hs[NH];
  __shared__ float red[256];
  __shared__ float h2[64];
  int row = blockIdx.x, tid = threadIdx.x;
#pragma unroll
  for (int q = 0; q < 4; ++q) hs[tid + q * 256] = h[(long)row * NH + tid + q * 256];
  __syncthreads();
  int c = tid >> 2, pp = tid & 3;
  float s = 0.f;
  for (int k = pp * 256; k < pp * 256 + 256; ++k) s += hs[k] * W1[k * 64 + c];
  red[tid] = s;
  __syncthreads();
  if (tid < 64) {
    float v = red[tid * 4] + red[tid * 4 + 1] + red[tid * 4 + 2] + red[tid * 4 + 3] + b1[tid];
    v = fmaxf(v, 0.f);
    h2[tid] = v * W3[tid];
  }
  __syncthreads();
  if (tid < 64) {
    float v = h2[tid];
#pragma unroll
    for (int o = 32; o; o >>= 1) v += __shfl_down(v, o);
    if (tid == 0) out[row] = 1.f / (1.f + __expf(-(v + b3[0])));
  }
}

extern "C" void kernel_launch(void* const* d_in, const int* in_sizes, int n_in,
                              void* d_out, int out_size, void* d_ws, size_t ws_size,
                              hipStream_t stream) {
  const float* x      = (const float*)d_in[0];
  const float* dist   = (const float*)d_in[1];
  const int*   adj    = (const int*)d_in[2];
  const float* fc_W   = (const float*)d_in[3];
  const float* fc_b   = (const float*)d_in[4];
  const float* conv_W = (const float*)d_in[5];
  const float* gat_W  = (const float*)d_in[6];
  const float* gat_a  = (const float*)d_in[7];
  const float* cls1_W = (const float*)d_in[8];
  const float* cls1_b = (const float*)d_in[9];
  const float* cls3_W = (const float*)d_in[10];
  const float* cls3_b = (const float*)d_in[11];
  float* out = (float*)d_out;

  char* p = (char*)d_ws;
  auto alloc = [&](size_t bytes) {
    char* r = p;
    p += (bytes + 255) & ~(size_t)255;
    return r;
  };
  unsigned short* distb  = (unsigned short*)alloc((size_t)NN * NN * 2);
  float* h0f             = (float*)alloc((size_t)NN * NH * 4);
  float* hf              = (float*)alloc((size_t)NN * NH * 4);
  float* supf            = (float*)alloc((size_t)NN * NH * 4);
  unsigned short* supb   = (unsigned short*)alloc((size_t)NN * NH * 2);
  unsigned short* hb     = (unsigned short*)alloc((size_t)NN * NH * 2);
  unsigned short* hTb    = (unsigned short*)alloc((size_t)NN * NH * 2);
  unsigned short* convWT = (unsigned short*)alloc((size_t)7 * NH * NH * 2);
  unsigned short* gatWT  = (unsigned short*)alloc((size_t)NH * NH * 2);
  float* va1 = (float*)alloc(NH * 4);
  float* va2 = (float*)alloc(NH * 4);
  float* fv  = (float*)alloc(NN * 4);
  float* gv  = (float*)alloc(NN * 4);
  float* Mr  = (float*)alloc(NN * 4);
  float* Lr  = (float*)alloc(NN * 4);

  float th[7];
  for (int l = 0; l < 7; ++l) {
    float t = logf(1.5f / (float)(l + 1) + 1.f);
    th[l] = t < 1.f ? t : 1.f;
  }
  float th9 = logf(1.5f / 9.f + 1.f);

  // dist -> bf16 (fits in L3; reused by 7 GEMMs)
  f32_to_bf16_vec<<<(NN * (long)NN) / (4 * 256), 256, 0, stream>>>(dist, distb);
  // pre-transpose weights to bf16 (Bt layout: n-major, k contiguous)
  for (int i = 0; i < 7; ++i)
    transpose_f32_bf16<<<dim3(32, 32), 256, 0, stream>>>(
        conv_W + (size_t)i * NH * NH, convWT + (size_t)i * NH * NH, NH, NH);
  transpose_f32_bf16<<<dim3(32, 32), 256, 0, stream>>>(gat_W, gatWT, NH, NH);

  // h0 = relu(x @ fc_W + b); h = h0
  fc_kernel<<<NN, 256, 0, stream>>>(x, fc_W, fc_b, h0f, hf);
  transpose_f32_bf16<<<dim3(NH / 32, NN / 32), 256, 0, stream>>>(hf, hTb, NN, NH);

  dim3 ggrid(NH / 128, NN / 128);
  for (int l = 0; l < 7; ++l) {
    // hi = dist @ h ; support = 0.3*hi + 0.7*h0
    gemm_bt<0><<<ggrid, 256, 0, stream>>>(distb, hTb, NN, h0f, supf, supb, 0.f);
    // h = relu(th*(support@W) + (1-th)*support + h)
    gemm_bt<1><<<ggrid, 256, 0, stream>>>(supb, convWT + (size_t)l * NH * NH, NH,
                                          supf, hf, hb, th[l]);
    transpose_f32_bf16<<<dim3(NH / 32, NN / 32), 256, 0, stream>>>(hf, hTb, NN, NH);
  }

  // GAT: f = h@(gat_W@a1), g = h@(gat_W@a2)
  wv_kernel<<<NH, 256, 0, stream>>>(gat_W, gat_a, va1, va2);
  fg_kernel<<<NN, 256, 0, stream>>>(hf, va1, va2, fv, gv);
  attn_ml<<<NN, 256, 0, stream>>>(adj, fv, gv, Mr, Lr);
  attn_p<<<(NN * (long)NN) / (4 * 256), 256, 0, stream>>>(adj, fv, gv, Mr, Lr, distb);

  // hi = P @ h ; support = 0.3*hi + 0.7*h0
  gemm_bt<0><<<ggrid, 256, 0, stream>>>(distb, hTb, NN, h0f, supf, supb, 0.f);
  // h = elu(th9*(support@gat_W) + (1-th9)*support + h)
  gemm_bt<2><<<ggrid, 256, 0, stream>>>(supb, gatWT, NH, supf, hf, hb, th9);

  // classifier head
  cls_kernel<<<NN, 256, 0, stream>>>(hf, cls1_W, cls1_b, cls3_W, cls3_b, out);
}

// Round 2
// 3423.871 us; speedup vs baseline: 1.0820x; 1.0820x over previous
//
#include <hip/hip_runtime.h>
#include <math.h>

#define NN 8192
#define NH 1024

typedef __bf16 bf16x8 __attribute__((ext_vector_type(8)));
typedef float floatx4 __attribute__((ext_vector_type(4)));
typedef unsigned short us8 __attribute__((ext_vector_type(8)));

__device__ __forceinline__ unsigned short f2bf(float f) {
  unsigned int u = __float_as_uint(f);
  u += 0x7fffu + ((u >> 16) & 1u);
  return (unsigned short)(u >> 16);
}

__device__ __forceinline__ void async16(const void* g, void* l) {
  __builtin_amdgcn_global_load_lds(
      (__attribute__((address_space(1))) void*)(g),
      (__attribute__((address_space(3))) void*)(l), 16, 0, 0);
}

// ================= big GEMM, split-K=2: partial = A(128-stripe) * Bt^T ======
// A: M x 8192 bf16 row-major; Bt: 1024 x 8192 bf16 (n-major). Grid: 1024 1D.
// swizzle: xcd = id&7; slot = id>>3; x = slot&7; g = xcd + 8*(slot>>3);
//          y = g&63 (M tile), z = g>>6 (K half). Partial z=0 -> p0, z=1 -> p1.
__global__ __launch_bounds__(256)
void gemm_part(const unsigned short* __restrict__ A,
               const unsigned short* __restrict__ Bt,
               float* __restrict__ p0, float* __restrict__ p1)
{
  __shared__ __align__(16) unsigned short lA[128 * 32];
  __shared__ __align__(16) unsigned short lB[128 * 32];
  const int id = blockIdx.x;
  const int xcd = id & 7, slot = id >> 3;
  const int xt = slot & 7;
  const int g = xcd + 8 * (slot >> 3);
  const int yt = g & 63;
  const int z = g >> 6;

  const int tid  = threadIdx.x;
  const int lane = tid & 63;
  const int wave = tid >> 6;
  const long tileM = (long)yt * 128;
  const long tileN = (long)xt * 128;
  const long kOff  = (long)z * 4096;
  const int wm = (wave & 1) * 64;
  const int wn = (wave >> 1) * 64;

  const int srow = lane >> 2;
  const int scol = (lane & 3) * 8;
  const int r0 = wave * 16 + srow;
  const int r1 = 64 + wave * 16 + srow;

  const unsigned short* gA0 = A + (tileM + r0) * 8192L + kOff + scol;
  const unsigned short* gA1 = A + (tileM + r1) * 8192L + kOff + scol;
  const unsigned short* gB0 = Bt + (tileN + r0) * 8192L + kOff + scol;
  const unsigned short* gB1 = Bt + (tileN + r1) * 8192L + kOff + scol;
  unsigned short* lA0 = &lA[r0 * 32 + scol];
  unsigned short* lA1 = &lA[r1 * 32 + scol];
  unsigned short* lB0 = &lB[r0 * 32 + scol];
  unsigned short* lB1 = &lB[r1 * 32 + scol];

  const int fr = lane & 15;
  const int q8 = (lane >> 4) * 8;

  floatx4 zero4 = {0.f, 0.f, 0.f, 0.f};
  floatx4 acc[4][4];
#pragma unroll
  for (int i = 0; i < 4; ++i)
#pragma unroll
    for (int j = 0; j < 4; ++j) acc[i][j] = zero4;

  for (int kt = 0; kt < 128; ++kt) {
    const int k0 = kt << 5;
    async16(gA0 + k0, lA0);
    async16(gA1 + k0, lA1);
    async16(gB0 + k0, lB0);
    async16(gB1 + k0, lB1);
    __syncthreads();
    bf16x8 af[4], bfr[4];
#pragma unroll
    for (int i = 0; i < 4; ++i)
      af[i] = *(const bf16x8*)&lA[(wm + 16 * i + fr) * 32 + q8];
#pragma unroll
    for (int j = 0; j < 4; ++j)
      bfr[j] = *(const bf16x8*)&lB[(wn + 16 * j + fr) * 32 + q8];
#pragma unroll
    for (int i = 0; i < 4; ++i)
#pragma unroll
      for (int j = 0; j < 4; ++j)
        acc[i][j] = __builtin_amdgcn_mfma_f32_16x16x32_bf16(af[i], bfr[j], acc[i][j], 0, 0, 0);
    __syncthreads();
  }

  float* outp = z ? p1 : p0;
  const int crow = (lane >> 4) * 4;
#pragma unroll
  for (int i = 0; i < 4; ++i)
#pragma unroll
    for (int j = 0; j < 4; ++j)
#pragma unroll
      for (int r = 0; r < 4; ++r) {
        long row = tileM + wm + 16 * i + crow + r;
        long col = tileN + wn + 16 * j + fr;
        outp[row * NH + col] = acc[i][j][r];
      }
}

// ============ fixup: sup = 0.3*(p0+p1) + 0.7*h0 -> supf (in-place p1), supb ==
__global__ __launch_bounds__(256)
void fixup_sup(const float* __restrict__ p0, float* __restrict__ p1_supf,
               const float* __restrict__ h0, unsigned short* __restrict__ supb)
{
  long i = (blockIdx.x * 256L + threadIdx.x) * 4;
  float4 a = *(const float4*)(p0 + i);
  float4 b = *(const float4*)(p1_supf + i);
  float4 c = *(const float4*)(h0 + i);
  float4 s;
  s.x = 0.3f * (a.x + b.x) + 0.7f * c.x;
  s.y = 0.3f * (a.y + b.y) + 0.7f * c.y;
  s.z = 0.3f * (a.z + b.z) + 0.7f * c.z;
  s.w = 0.3f * (a.w + b.w) + 0.7f * c.w;
  *(float4*)(p1_supf + i) = s;
  *(ushort4*)(supb + i) = make_ushort4(f2bf(s.x), f2bf(s.y), f2bf(s.z), f2bf(s.w));
}

// ========== small GEMM K=1024 + epilogue (+optional fused transpose) ========
// o = th*(sup@W) + (1-th)*sup + h ; ACT 1=relu, 2=elu. writes hf (fp32) and,
// if TRANS, hTb (bf16, transposed 1024x8192). Grid: 512 1D, swizzled.
template<int ACT, bool TRANS>
__global__ __launch_bounds__(256)
void gemm_ep(const unsigned short* __restrict__ A,   // supb 8192x1024
             const unsigned short* __restrict__ Bt,  // W^T bf16 1024x1024
             const float* __restrict__ supf,
             float* __restrict__ hf,
             unsigned short* __restrict__ hTb,
             float theta)
{
  __shared__ __align__(16) char smem[TRANS ? (128 * 136 * 2) : 32768];
  unsigned short* lA = (unsigned short*)smem;
  unsigned short* lB = (unsigned short*)(smem + 16384);

  const int id = blockIdx.x;
  const int xcd = id & 7, slot = id >> 3;
  const int xt = slot & 7;
  const int yt = xcd + 8 * (slot >> 3);

  const int tid  = threadIdx.x;
  const int lane = tid & 63;
  const int wave = tid >> 6;
  const long tileM = (long)yt * 128;
  const long tileN = (long)xt * 128;
  const int wm = (wave & 1) * 64;
  const int wn = (wave >> 1) * 64;

  const int srow = lane >> 2;
  const int scol = (lane & 3) * 8;
  const int r0 = wave * 16 + srow;
  const int r1 = 64 + wave * 16 + srow;

  const unsigned short* gA0 = A + (tileM + r0) * 1024L + scol;
  const unsigned short* gA1 = A + (tileM + r1) * 1024L + scol;
  const unsigned short* gB0 = Bt + (tileN + r0) * 1024L + scol;
  const unsigned short* gB1 = Bt + (tileN + r1) * 1024L + scol;
  unsigned short* lA0 = &lA[r0 * 32 + scol];
  unsigned short* lA1 = &lA[r1 * 32 + scol];
  unsigned short* lB0 = &lB[r0 * 32 + scol];
  unsigned short* lB1 = &lB[r1 * 32 + scol];

  const int fr = lane & 15;
  const int q8 = (lane >> 4) * 8;

  floatx4 zero4 = {0.f, 0.f, 0.f, 0.f};
  floatx4 acc[4][4];
#pragma unroll
  for (int i = 0; i < 4; ++i)
#pragma unroll
    for (int j = 0; j < 4; ++j) acc[i][j] = zero4;

  for (int kt = 0; kt < 32; ++kt) {
    const int k0 = kt << 5;
    async16(gA0 + k0, lA0);
    async16(gA1 + k0, lA1);
    async16(gB0 + k0, lB0);
    async16(gB1 + k0, lB1);
    __syncthreads();
    bf16x8 af[4], bfr[4];
#pragma unroll
    for (int i = 0; i < 4; ++i)
      af[i] = *(const bf16x8*)&lA[(wm + 16 * i + fr) * 32 + q8];
#pragma unroll
    for (int j = 0; j < 4; ++j)
      bfr[j] = *(const bf16x8*)&lB[(wn + 16 * j + fr) * 32 + q8];
#pragma unroll
    for (int i = 0; i < 4; ++i)
#pragma unroll
      for (int j = 0; j < 4; ++j)
        acc[i][j] = __builtin_amdgcn_mfma_f32_16x16x32_bf16(af[i], bfr[j], acc[i][j], 0, 0, 0);
    __syncthreads();
  }

  unsigned short* ldsT = (unsigned short*)smem;  // [c][r], stride 136
  const int crow = (lane >> 4) * 4;
#pragma unroll
  for (int i = 0; i < 4; ++i)
#pragma unroll
    for (int j = 0; j < 4; ++j)
#pragma unroll
      for (int r = 0; r < 4; ++r) {
        int lr = wm + 16 * i + crow + r;      // local row (M)
        int lc = wn + 16 * j + fr;            // local col (N)
        long idx = (tileM + lr) * NH + tileN + lc;
        float o = theta * acc[i][j][r] + (1.f - theta) * supf[idx] + hf[idx];
        o = (ACT == 1) ? fmaxf(o, 0.f) : (o > 0.f ? o : __expf(o) - 1.f);
        hf[idx] = o;
        if (TRANS) ldsT[lc * 136 + lr] = f2bf(o);
      }
  if (TRANS) {
    __syncthreads();
    int c = tid >> 1, half = tid & 1;
#pragma unroll
    for (int it = 0; it < 8; ++it) {
      int r = half * 64 + it * 8;
      us8 v = *(const us8*)&ldsT[c * 136 + r];
      *(us8*)&hTb[(tileN + c) * 8192L + tileM + r] = v;
    }
  }
}

// ---------------- fp32 (R x C) -> bf16 transposed (C x R) ----------------
__global__ __launch_bounds__(256)
void transpose_f32_bf16(const float* __restrict__ src, unsigned short* __restrict__ dst,
                        int R, int C) {
  __shared__ float t[32][33];
  int tid = threadIdx.x;
  int tx = tid & 31, ty = tid >> 5;
  long r0 = (long)blockIdx.y * 32, c0 = (long)blockIdx.x * 32;
#pragma unroll
  for (int i = 0; i < 32; i += 8)
    t[ty + i][tx] = src[(r0 + ty + i) * C + c0 + tx];
  __syncthreads();
#pragma unroll
  for (int i = 0; i < 32; i += 8)
    dst[(c0 + ty + i) * R + r0 + tx] = f2bf(t[tx][ty + i]);
}

// ---------------- fp32 -> bf16 elementwise (dist) ----------------
__global__ __launch_bounds__(256)
void f32_to_bf16_vec(const float* __restrict__ s, unsigned short* __restrict__ d) {
  long i = (blockIdx.x * 256L + threadIdx.x) * 4;
  float4 v = *(const float4*)(s + i);
  *(ushort4*)(d + i) = make_ushort4(f2bf(v.x), f2bf(v.y), f2bf(v.z), f2bf(v.w));
}

// ---------------- h0 = relu(x @ fc_W + fc_b) ----------------
__global__ __launch_bounds__(256)
void fc_kernel(const float* __restrict__ x, const float* __restrict__ W,
               const float* __restrict__ b, float* __restrict__ h0f,
               float* __restrict__ hf) {
  __shared__ float xs[64];
  int row = blockIdx.x, tid = threadIdx.x;
  if (tid < 63) xs[tid] = x[row * 63 + tid];
  __syncthreads();
#pragma unroll
  for (int q = 0; q < 4; ++q) {
    int c = tid + q * 256;
    float s = b[c];
    for (int k = 0; k < 63; ++k) s += xs[k] * W[k * NH + c];
    s = fmaxf(s, 0.f);
    long idx = (long)row * NH + c;
    h0f[idx] = s;
    hf[idx] = s;
  }
}

// ---------------- va1 = gat_W @ a1, va2 = gat_W @ a2 ----------------
__global__ __launch_bounds__(256)
void wv_kernel(const float* __restrict__ W, const float* __restrict__ a,
               float* __restrict__ va1, float* __restrict__ va2) {
  int k = blockIdx.x, tid = threadIdx.x;
  float s1 = 0.f, s2 = 0.f;
  for (int n = tid; n < NH; n += 256) {
    float w = W[(long)k * NH + n];
    s1 += w * a[n];
    s2 += w * a[NH + n];
  }
#pragma unroll
  for (int o = 32; o; o >>= 1) { s1 += __shfl_down(s1, o); s2 += __shfl_down(s2, o); }
  __shared__ float r1[4], r2[4];
  int wave = tid >> 6;
  if ((tid & 63) == 0) { r1[wave] = s1; r2[wave] = s2; }
  __syncthreads();
  if (tid == 0) {
    va1[k] = r1[0] + r1[1] + r1[2] + r1[3];
    va2[k] = r2[0] + r2[1] + r2[2] + r2[3];
  }
}

// ---------------- f = h @ va1, g = h @ va2 ----------------
__global__ __launch_bounds__(256)
void fg_kernel(const float* __restrict__ h, const float* __restrict__ va1,
               const float* __restrict__ va2, float* __restrict__ fv,
               float* __restrict__ gv) {
  int row = blockIdx.x, tid = threadIdx.x;
  float s1 = 0.f, s2 = 0.f;
  for (int k = tid; k < NH; k += 256) {
    float v = h[(long)row * NH + k];
    s1 += v * va1[k];
    s2 += v * va2[k];
  }
#pragma unroll
  for (int o = 32; o; o >>= 1) { s1 += __shfl_down(s1, o); s2 += __shfl_down(s2, o); }
  __shared__ float r1[4], r2[4];
  int wave = tid >> 6;
  if ((tid & 63) == 0) { r1[wave] = s1; r2[wave] = s2; }
  __syncthreads();
  if (tid == 0) {
    fv[row] = r1[0] + r1[1] + r1[2] + r1[3];
    gv[row] = r2[0] + r2[1] + r2[2] + r2[3];
  }
}

// ---------------- attention pass 1: per-row max & denom ----------------
__global__ __launch_bounds__(256)
void attn_ml(const int* __restrict__ adj, const float* __restrict__ f,
             const float* __restrict__ g, float* __restrict__ Mr,
             float* __restrict__ Lr) {
  const int row = blockIdx.x, tid = threadIdx.x;
  const float fi = f[row];
  const int4* arow = (const int4*)(adj + (long)row * NN);
  float m = -3.0e38f, s = 0.f;
  for (int c = tid; c < NN / 4; c += 256) {
    int4 a = arow[c];
    float4 gg = *(const float4*)(g + c * 4);
#pragma unroll
    for (int t = 0; t < 4; ++t) {
      int av = (t == 0) ? a.x : (t == 1) ? a.y : (t == 2) ? a.z : a.w;
      float gvv = (t == 0) ? gg.x : (t == 1) ? gg.y : (t == 2) ? gg.z : gg.w;
      if (av > 0) {
        float e = fi + gvv;
        e = e > 0.f ? e : 0.2f * e;
        if (e > m) { s = s * __expf(m - e) + 1.f; m = e; }
        else s += __expf(e - m);
      }
    }
  }
#pragma unroll
  for (int o = 32; o; o >>= 1) {
    float m2 = __shfl_down(m, o), s2 = __shfl_down(s, o);
    float mn = fmaxf(m, m2);
    s = s * __expf(m - mn) + s2 * __expf(m2 - mn);
    m = mn;
  }
  __shared__ float ms[4], ss[4];
  int wave = tid >> 6;
  if ((tid & 63) == 0) { ms[wave] = m; ss[wave] = s; }
  __syncthreads();
  if (tid == 0) {
    float mm = ms[0], sv = ss[0];
    for (int w = 1; w < 4; ++w) {
      float mn = fmaxf(mm, ms[w]);
      sv = sv * __expf(mm - mn) + ss[w] * __expf(ms[w] - mn);
      mm = mn;
    }
    Mr[row] = mm;
    Lr[row] = sv;
  }
}

// ---------------- attention pass 2: P (bf16) ----------------
__global__ __launch_bounds__(256)
void attn_p(const int* __restrict__ adj, const float* __restrict__ f,
            const float* __restrict__ g, const float* __restrict__ Mr,
            const float* __restrict__ Lr, unsigned short* __restrict__ P) {
  long gid = blockIdx.x * 256L + threadIdx.x;
  int row = (int)(gid >> 11);
  int jc = (int)(gid & 2047) * 4;
  float fi = f[row], m = Mr[row], l = Lr[row];
  bool uni = !(l > 0.f);
  float inv = uni ? 0.f : 1.f / l;
  int4 a = *(const int4*)(adj + ((long)row << 13) + jc);
  float4 gg = *(const float4*)(g + jc);
  float p[4];
#pragma unroll
  for (int t = 0; t < 4; ++t) {
    int av = (t == 0) ? a.x : (t == 1) ? a.y : (t == 2) ? a.z : a.w;
    float gvv = (t == 0) ? gg.x : (t == 1) ? gg.y : (t == 2) ? gg.z : gg.w;
    float e = fi + gvv;
    e = e > 0.f ? e : 0.2f * e;
    float pv = (av > 0) ? __expf(e - m) * inv : 0.f;
    if (uni) pv = 1.f / (float)NN;
    p[t] = pv;
  }
  *(ushort4*)(P + ((long)row << 13) + jc) =
      make_ushort4(f2bf(p[0]), f2bf(p[1]), f2bf(p[2]), f2bf(p[3]));
}

// ---------------- classifier head ----------------
__global__ __launch_bounds__(256)
void cls_kernel(const float* __restrict__ h, const float* __restrict__ W1,
                const float* __restrict__ b1, const float* __restrict__ W3,
                const float* __restrict__ b3, float* __restrict__ out) {
  __shared__ float hs[NH];
  __shared__ float red[256];
  __shared__ float h2[64];
  int row = blockIdx.x, tid = threadIdx.x;
#pragma unroll
  for (int q = 0; q < 4; ++q) hs[tid + q * 256] = h[(long)row * NH + tid + q * 256];
  __syncthreads();
  int c = tid >> 2, pp = tid & 3;
  float s = 0.f;
  for (int k = pp * 256; k < pp * 256 + 256; ++k) s += hs[k] * W1[k * 64 + c];
  red[tid] = s;
  __syncthreads();
  if (tid < 64) {
    float v = red[tid * 4] + red[tid * 4 + 1] + red[tid * 4 + 2] + red[tid * 4 + 3] + b1[tid];
    v = fmaxf(v, 0.f);
    h2[tid] = v * W3[tid];
  }
  __syncthreads();
  if (tid < 64) {
    float v = h2[tid];
#pragma unroll
    for (int o = 32; o; o >>= 1) v += __shfl_down(v, o);
    if (tid == 0) out[row] = 1.f / (1.f + __expf(-(v + b3[0])));
  }
}

extern "C" void kernel_launch(void* const* d_in, const int* in_sizes, int n_in,
                              void* d_out, int out_size, void* d_ws, size_t ws_size,
                              hipStream_t stream) {
  const float* x      = (const float*)d_in[0];
  const float* dist   = (const float*)d_in[1];
  const int*   adj    = (const int*)d_in[2];
  const float* fc_W   = (const float*)d_in[3];
  const float* fc_b   = (const float*)d_in[4];
  const float* conv_W = (const float*)d_in[5];
  const float* gat_W  = (const float*)d_in[6];
  const float* gat_a  = (const float*)d_in[7];
  const float* cls1_W = (const float*)d_in[8];
  const float* cls1_b = (const float*)d_in[9];
  const float* cls3_W = (const float*)d_in[10];
  const float* cls3_b = (const float*)d_in[11];
  float* out = (float*)d_out;

  char* p = (char*)d_ws;
  auto alloc = [&](size_t bytes) {
    char* r = p;
    p += (bytes + 255) & ~(size_t)255;
    return r;
  };
  unsigned short* distb  = (unsigned short*)alloc((size_t)NN * NN * 2);
  float* h0f             = (float*)alloc((size_t)NN * NH * 4);
  float* hf              = (float*)alloc((size_t)NN * NH * 4);
  float* supf            = (float*)alloc((size_t)NN * NH * 4);  // also p1
  float* part0           = (float*)alloc((size_t)NN * NH * 4);  // p0
  unsigned short* supb   = (unsigned short*)alloc((size_t)NN * NH * 2);
  unsigned short* hTb    = (unsigned short*)alloc((size_t)NN * NH * 2);
  unsigned short* convWT = (unsigned short*)alloc((size_t)7 * NH * NH * 2);
  unsigned short* gatWT  = (unsigned short*)alloc((size_t)NH * NH * 2);
  float* va1 = (float*)alloc(NH * 4);
  float* va2 = (float*)alloc(NH * 4);
  float* fv  = (float*)alloc(NN * 4);
  float* gv  = (float*)alloc(NN * 4);
  float* Mr  = (float*)alloc(NN * 4);
  float* Lr  = (float*)alloc(NN * 4);

  float th[7];
  for (int l = 0; l < 7; ++l) {
    float t = logf(1.5f / (float)(l + 1) + 1.f);
    th[l] = t < 1.f ? t : 1.f;
  }
  float th9 = logf(1.5f / 9.f + 1.f);

  // dist -> bf16
  f32_to_bf16_vec<<<(NN * (long)NN) / (4 * 256), 256, 0, stream>>>(dist, distb);
  for (int i = 0; i < 7; ++i)
    transpose_f32_bf16<<<dim3(32, 32), 256, 0, stream>>>(
        conv_W + (size_t)i * NH * NH, convWT + (size_t)i * NH * NH, NH, NH);
  transpose_f32_bf16<<<dim3(32, 32), 256, 0, stream>>>(gat_W, gatWT, NH, NH);

  fc_kernel<<<NN, 256, 0, stream>>>(x, fc_W, fc_b, h0f, hf);
  transpose_f32_bf16<<<dim3(NH / 32, NN / 32), 256, 0, stream>>>(hf, hTb, NN, NH);

  const int fixup_grid = (NN * NH) / (4 * 256);
  for (int l = 0; l < 7; ++l) {
    gemm_part<<<1024, 256, 0, stream>>>(distb, hTb, part0, supf);
    fixup_sup<<<fixup_grid, 256, 0, stream>>>(part0, supf, h0f, supb);
    gemm_ep<1, true><<<512, 256, 0, stream>>>(supb, convWT + (size_t)l * NH * NH,
                                              supf, hf, hTb, th[l]);
  }

  // GAT
  wv_kernel<<<NH, 256, 0, stream>>>(gat_W, gat_a, va1, va2);
  fg_kernel<<<NN, 256, 0, stream>>>(hf, va1, va2, fv, gv);
  attn_ml<<<NN, 256, 0, stream>>>(adj, fv, gv, Mr, Lr);
  attn_p<<<(NN * (long)NN) / (4 * 256), 256, 0, stream>>>(adj, fv, gv, Mr, Lr, distb);

  gemm_part<<<1024, 256, 0, stream>>>(distb, hTb, part0, supf);
  fixup_sup<<<fixup_grid, 256, 0, stream>>>(part0, supf, h0f, supb);
  gemm_ep<2, false><<<512, 256, 0, stream>>>(supb, gatWT, supf, hf, nullptr, th9);

  cls_kernel<<<NN, 256, 0, stream>>>(hf, cls1_W, cls1_b, cls3_W, cls3_b, out);
}

// Round 3
// 2510.185 us; speedup vs baseline: 1.4758x; 1.3640x over previous
//
#include <hip/hip_runtime.h>
#include <math.h>

#define NN 8192
#define NH 1024

typedef __bf16 bf16x8 __attribute__((ext_vector_type(8)));
typedef float floatx4 __attribute__((ext_vector_type(4)));
typedef unsigned short us8 __attribute__((ext_vector_type(8)));
typedef unsigned short us;

__device__ __forceinline__ unsigned short f2bf(float f) {
  unsigned int u = __float_as_uint(f);
  u += 0x7fffu + ((u >> 16) & 1u);
  return (unsigned short)(u >> 16);
}

__device__ __forceinline__ void async16(const void* g, void* l) {
  __builtin_amdgcn_global_load_lds(
      (__attribute__((address_space(1))) void*)(g),
      (__attribute__((address_space(3))) void*)(l), 16, 0, 0);
}

// ============ double-buffered GEMM: C = A(8192 x K) * Bt(128N x K)^T =========
// grid 512 (64 M-tiles x 8 N-tiles), XCD-swizzled. LDS dbuf: loads for tile
// kt+1 issued right after the barrier, overlapped with compute of tile kt.
// EPI 0: s = 0.3*acc + 0.7*aux(h0);            write iof(supf), outb(supb)
// EPI 1: o = relu(th*acc + (1-th)*aux + iof);  write iof(hf), fused-T -> hTb
// EPI 2: o = elu(...);                         write iof(hf), outb(hb)
template<int EPI>
__global__ __launch_bounds__(256)
void gemm_db(const us* __restrict__ A, const us* __restrict__ Bt, int K,
             const float* __restrict__ aux, float* __restrict__ iof,
             us* __restrict__ outb, us* __restrict__ hTb, float theta)
{
  __shared__ __align__(16) us lsm[EPI == 1 ? 17408 : 16384];
  const int id = blockIdx.x;
  const int xcd = id & 7, slot = id >> 3;
  const int xt = slot & 7;
  const int yt = xcd + 8 * (slot >> 3);

  const int tid  = threadIdx.x;
  const int lane = tid & 63;
  const int wave = tid >> 6;
  const long tileM = (long)yt * 128;
  const long tileN = (long)xt * 128;
  const int wm = (wave & 1) * 64;
  const int wn = (wave >> 1) * 64;

  const us* gA0 = A + (tileM + (tid >> 2)) * (long)K + (tid & 3) * 8;
  const us* gA1 = gA0 + 64L * K;
  const us* gB0 = Bt + (tileN + (tid >> 2)) * (long)K + (tid & 3) * 8;
  const us* gB1 = gB0 + 64L * K;
  us* lA = lsm;              // two 4096-us buffers
  us* lB = lsm + 8192;       // two 4096-us buffers
  const int lo = tid * 8;

  const int fr = lane & 15;
  const int q8 = (lane >> 4) * 8;

  floatx4 zero4 = {0.f, 0.f, 0.f, 0.f};
  floatx4 acc[4][4];
#pragma unroll
  for (int i = 0; i < 4; ++i)
#pragma unroll
    for (int j = 0; j < 4; ++j) acc[i][j] = zero4;

  // prologue: stage tile 0 into buffer 0
  async16(gA0, lA + lo);
  async16(gA1, lA + lo + 2048);
  async16(gB0, lB + lo);
  async16(gB1, lB + lo + 2048);

  const int nkt = K >> 5;
  for (int kt = 0; kt < nkt; ++kt) {
    const int b = (kt & 1) << 12;
    __syncthreads();  // buffer b staged (compiler drains vmcnt before barrier)
    if (kt + 1 < nkt) {
      const int k0 = (kt + 1) << 5;
      const int b2 = b ^ 4096;
      async16(gA0 + k0, lA + b2 + lo);
      async16(gA1 + k0, lA + b2 + lo + 2048);
      async16(gB0 + k0, lB + b2 + lo);
      async16(gB1 + k0, lB + b2 + lo + 2048);
    }
    bf16x8 af[4], bfr[4];
#pragma unroll
    for (int i = 0; i < 4; ++i)
      af[i] = *(const bf16x8*)&lA[b + (wm + 16 * i + fr) * 32 + q8];
#pragma unroll
    for (int j = 0; j < 4; ++j)
      bfr[j] = *(const bf16x8*)&lB[b + (wn + 16 * j + fr) * 32 + q8];
#pragma unroll
    for (int i = 0; i < 4; ++i)
#pragma unroll
      for (int j = 0; j < 4; ++j)
        acc[i][j] = __builtin_amdgcn_mfma_f32_16x16x32_bf16(af[i], bfr[j], acc[i][j], 0, 0, 0);
  }

  if (EPI == 1) __syncthreads();  // protect lsm reuse (transpose buffer)
  us* ldsT = lsm;                 // [col][row], stride 136
  const int crow = (lane >> 4) * 4;
#pragma unroll
  for (int i = 0; i < 4; ++i) {
#pragma unroll
    for (int j = 0; j < 4; ++j) {
#pragma unroll
      for (int r = 0; r < 4; ++r) {
        int lr = wm + 16 * i + crow + r;
        int lc = wn + 16 * j + fr;
        long idx = (tileM + lr) * NH + tileN + lc;
        float v = acc[i][j][r];
        if (EPI == 0) {
          float s = 0.3f * v + 0.7f * aux[idx];
          iof[idx] = s;
          outb[idx] = f2bf(s);
        } else {
          float o = theta * v + (1.f - theta) * aux[idx] + iof[idx];
          o = (EPI == 1) ? fmaxf(o, 0.f) : (o > 0.f ? o : __expf(o) - 1.f);
          iof[idx] = o;
          if (EPI == 1) ldsT[lc * 136 + lr] = f2bf(o);
          if (EPI == 2) outb[idx] = f2bf(o);
        }
      }
    }
  }
  if (EPI == 1) {
    __syncthreads();
    int c = tid >> 1, half = tid & 1;
#pragma unroll
    for (int it = 0; it < 8; ++it) {
      int r = half * 64 + it * 8;
      us8 v = *(const us8*)&ldsT[c * 136 + r];
      *(us8*)&hTb[(tileN + c) * 8192L + tileM + r] = v;
    }
  }
}

// ======== classifier head as MFMA GEMM: out = sigmoid(relu(h@W1+b1)@W3+b3) ===
// hb: 8192x1024 bf16, W1t: 64x1024 bf16. Grid 64 blocks x 256 thr.
__global__ __launch_bounds__(256)
void cls_gemm(const us* __restrict__ hb, const us* __restrict__ W1t,
              const float* __restrict__ b1, const float* __restrict__ W3,
              const float* __restrict__ b3, float* __restrict__ out)
{
  __shared__ __align__(16) us lA[4096];
  __shared__ __align__(16) us lB[2048];
  const int tid = threadIdx.x, lane = tid & 63, wave = tid >> 6;
  const long tileM = (long)blockIdx.x * 128;
  const us* gA0 = hb + (tileM + (tid >> 2)) * 1024L + (tid & 3) * 8;
  const us* gA1 = gA0 + 64 * 1024L;
  const us* gB0 = W1t + (tid >> 2) * 1024L + (tid & 3) * 8;
  const int fr = lane & 15, q8 = (lane >> 4) * 8;
  const int wm = wave * 32;

  floatx4 zero4 = {0.f, 0.f, 0.f, 0.f};
  floatx4 acc[2][4];
#pragma unroll
  for (int i = 0; i < 2; ++i)
#pragma unroll
    for (int j = 0; j < 4; ++j) acc[i][j] = zero4;

  for (int kt = 0; kt < 32; ++kt) {
    const int k0 = kt << 5;
    async16(gA0 + k0, lA + tid * 8);
    async16(gA1 + k0, lA + 2048 + tid * 8);
    async16(gB0 + k0, lB + tid * 8);
    __syncthreads();
    bf16x8 af[2], bfr[4];
#pragma unroll
    for (int i = 0; i < 2; ++i)
      af[i] = *(const bf16x8*)&lA[(wm + 16 * i + fr) * 32 + q8];
#pragma unroll
    for (int j = 0; j < 4; ++j)
      bfr[j] = *(const bf16x8*)&lB[(16 * j + fr) * 32 + q8];
#pragma unroll
    for (int i = 0; i < 2; ++i)
#pragma unroll
      for (int j = 0; j < 4; ++j)
        acc[i][j] = __builtin_amdgcn_mfma_f32_16x16x32_bf16(af[i], bfr[j], acc[i][j], 0, 0, 0);
    __syncthreads();
  }

  float b1v[4], w3v[4];
#pragma unroll
  for (int j = 0; j < 4; ++j) { b1v[j] = b1[16 * j + fr]; w3v[j] = W3[16 * j + fr]; }
  const float b3v = b3[0];
  const int crow = (lane >> 4) * 4;
#pragma unroll
  for (int i = 0; i < 2; ++i)
#pragma unroll
    for (int r = 0; r < 4; ++r) {
      float v = 0.f;
#pragma unroll
      for (int j = 0; j < 4; ++j)
        v += fmaxf(acc[i][j][r] + b1v[j], 0.f) * w3v[j];
      v += __shfl_xor(v, 1);
      v += __shfl_xor(v, 2);
      v += __shfl_xor(v, 4);
      v += __shfl_xor(v, 8);
      if (fr == 0)
        out[tileM + wm + 16 * i + crow + r] = 1.f / (1.f + __expf(-(v + b3v)));
    }
}

// ---------------- fp32 (R x C) -> bf16 transposed (C x R) ----------------
__global__ __launch_bounds__(256)
void transpose_f32_bf16(const float* __restrict__ src, us* __restrict__ dst,
                        int R, int C) {
  __shared__ float t[32][33];
  int tid = threadIdx.x;
  int tx = tid & 31, ty = tid >> 5;
  long r0 = (long)blockIdx.y * 32, c0 = (long)blockIdx.x * 32;
#pragma unroll
  for (int i = 0; i < 32; i += 8)
    t[ty + i][tx] = src[(r0 + ty + i) * C + c0 + tx];
  __syncthreads();
#pragma unroll
  for (int i = 0; i < 32; i += 8)
    dst[(c0 + ty + i) * R + r0 + tx] = f2bf(t[tx][ty + i]);
}

// ---------------- fp32 -> bf16 elementwise (dist) ----------------
__global__ __launch_bounds__(256)
void f32_to_bf16_vec(const float* __restrict__ s, us* __restrict__ d) {
  long i = (blockIdx.x * 256L + threadIdx.x) * 4;
  float4 v = *(const float4*)(s + i);
  *(ushort4*)(d + i) = make_ushort4(f2bf(v.x), f2bf(v.y), f2bf(v.z), f2bf(v.w));
}

// ---------------- h0 = relu(x @ fc_W + fc_b) ----------------
__global__ __launch_bounds__(256)
void fc_kernel(const float* __restrict__ x, const float* __restrict__ W,
               const float* __restrict__ b, float* __restrict__ h0f,
               float* __restrict__ hf) {
  __shared__ float xs[64];
  int row = blockIdx.x, tid = threadIdx.x;
  if (tid < 63) xs[tid] = x[row * 63 + tid];
  __syncthreads();
#pragma unroll
  for (int q = 0; q < 4; ++q) {
    int c = tid + q * 256;
    float s = b[c];
    for (int k = 0; k < 63; ++k) s += xs[k] * W[k * NH + c];
    s = fmaxf(s, 0.f);
    long idx = (long)row * NH + c;
    h0f[idx] = s;
    hf[idx] = s;
  }
}

// ---------------- va1 = gat_W @ a1, va2 = gat_W @ a2 ----------------
__global__ __launch_bounds__(256)
void wv_kernel(const float* __restrict__ W, const float* __restrict__ a,
               float* __restrict__ va1, float* __restrict__ va2) {
  int k = blockIdx.x, tid = threadIdx.x;
  float s1 = 0.f, s2 = 0.f;
  for (int n = tid; n < NH; n += 256) {
    float w = W[(long)k * NH + n];
    s1 += w * a[n];
    s2 += w * a[NH + n];
  }
#pragma unroll
  for (int o = 32; o; o >>= 1) { s1 += __shfl_down(s1, o); s2 += __shfl_down(s2, o); }
  __shared__ float r1[4], r2[4];
  int wave = tid >> 6;
  if ((tid & 63) == 0) { r1[wave] = s1; r2[wave] = s2; }
  __syncthreads();
  if (tid == 0) {
    va1[k] = r1[0] + r1[1] + r1[2] + r1[3];
    va2[k] = r2[0] + r2[1] + r2[2] + r2[3];
  }
}

// ---------------- f = h @ va1, g = h @ va2 ----------------
__global__ __launch_bounds__(256)
void fg_kernel(const float* __restrict__ h, const float* __restrict__ va1,
               const float* __restrict__ va2, float* __restrict__ fv,
               float* __restrict__ gv) {
  int row = blockIdx.x, tid = threadIdx.x;
  float s1 = 0.f, s2 = 0.f;
  for (int k = tid; k < NH; k += 256) {
    float v = h[(long)row * NH + k];
    s1 += v * va1[k];
    s2 += v * va2[k];
  }
#pragma unroll
  for (int o = 32; o; o >>= 1) { s1 += __shfl_down(s1, o); s2 += __shfl_down(s2, o); }
  __shared__ float r1[4], r2[4];
  int wave = tid >> 6;
  if ((tid & 63) == 0) { r1[wave] = s1; r2[wave] = s2; }
  __syncthreads();
  if (tid == 0) {
    fv[row] = r1[0] + r1[1] + r1[2] + r1[3];
    gv[row] = r2[0] + r2[1] + r2[2] + r2[3];
  }
}

// ---------------- attention pass 1: per-row max & denom ----------------
__global__ __launch_bounds__(256)
void attn_ml(const int* __restrict__ adj, const float* __restrict__ f,
             const float* __restrict__ g, float* __restrict__ Mr,
             float* __restrict__ Lr) {
  const int row = blockIdx.x, tid = threadIdx.x;
  const float fi = f[row];
  const int4* arow = (const int4*)(adj + (long)row * NN);
  float m = -3.0e38f, s = 0.f;
  for (int c = tid; c < NN / 4; c += 256) {
    int4 a = arow[c];
    float4 gg = *(const float4*)(g + c * 4);
#pragma unroll
    for (int t = 0; t < 4; ++t) {
      int av = (t == 0) ? a.x : (t == 1) ? a.y : (t == 2) ? a.z : a.w;
      float gvv = (t == 0) ? gg.x : (t == 1) ? gg.y : (t == 2) ? gg.z : gg.w;
      if (av > 0) {
        float e = fi + gvv;
        e = e > 0.f ? e : 0.2f * e;
        if (e > m) { s = s * __expf(m - e) + 1.f; m = e; }
        else s += __expf(e - m);
      }
    }
  }
#pragma unroll
  for (int o = 32; o; o >>= 1) {
    float m2 = __shfl_down(m, o), s2 = __shfl_down(s, o);
    float mn = fmaxf(m, m2);
    s = s * __expf(m - mn) + s2 * __expf(m2 - mn);
    m = mn;
  }
  __shared__ float ms[4], ss[4];
  int wave = tid >> 6;
  if ((tid & 63) == 0) { ms[wave] = m; ss[wave] = s; }
  __syncthreads();
  if (tid == 0) {
    float mm = ms[0], sv = ss[0];
    for (int w = 1; w < 4; ++w) {
      float mn = fmaxf(mm, ms[w]);
      sv = sv * __expf(mm - mn) + ss[w] * __expf(ms[w] - mn);
      mm = mn;
    }
    Mr[row] = mm;
    Lr[row] = sv;
  }
}

// ---------------- attention pass 2: P (bf16) ----------------
__global__ __launch_bounds__(256)
void attn_p(const int* __restrict__ adj, const float* __restrict__ f,
            const float* __restrict__ g, const float* __restrict__ Mr,
            const float* __restrict__ Lr, us* __restrict__ P) {
  long gid = blockIdx.x * 256L + threadIdx.x;
  int row = (int)(gid >> 11);
  int jc = (int)(gid & 2047) * 4;
  float fi = f[row], m = Mr[row], l = Lr[row];
  bool uni = !(l > 0.f);
  float inv = uni ? 0.f : 1.f / l;
  int4 a = *(const int4*)(adj + ((long)row << 13) + jc);
  float4 gg = *(const float4*)(g + jc);
  float p[4];
#pragma unroll
  for (int t = 0; t < 4; ++t) {
    int av = (t == 0) ? a.x : (t == 1) ? a.y : (t == 2) ? a.z : a.w;
    float gvv = (t == 0) ? gg.x : (t == 1) ? gg.y : (t == 2) ? gg.z : gg.w;
    float e = fi + gvv;
    e = e > 0.f ? e : 0.2f * e;
    float pv = (av > 0) ? __expf(e - m) * inv : 0.f;
    if (uni) pv = 1.f / (float)NN;
    p[t] = pv;
  }
  *(ushort4*)(P + ((long)row << 13) + jc) =
      make_ushort4(f2bf(p[0]), f2bf(p[1]), f2bf(p[2]), f2bf(p[3]));
}

extern "C" void kernel_launch(void* const* d_in, const int* in_sizes, int n_in,
                              void* d_out, int out_size, void* d_ws, size_t ws_size,
                              hipStream_t stream) {
  const float* x      = (const float*)d_in[0];
  const float* dist   = (const float*)d_in[1];
  const int*   adj    = (const int*)d_in[2];
  const float* fc_W   = (const float*)d_in[3];
  const float* fc_b   = (const float*)d_in[4];
  const float* conv_W = (const float*)d_in[5];
  const float* gat_W  = (const float*)d_in[6];
  const float* gat_a  = (const float*)d_in[7];
  const float* cls1_W = (const float*)d_in[8];
  const float* cls1_b = (const float*)d_in[9];
  const float* cls3_W = (const float*)d_in[10];
  const float* cls3_b = (const float*)d_in[11];
  float* out = (float*)d_out;

  char* p = (char*)d_ws;
  auto alloc = [&](size_t bytes) {
    char* r = p;
    p += (bytes + 255) & ~(size_t)255;
    return r;
  };
  us* distb   = (us*)alloc((size_t)NN * NN * 2);
  float* h0f  = (float*)alloc((size_t)NN * NH * 4);
  float* hf   = (float*)alloc((size_t)NN * NH * 4);
  float* supf = (float*)alloc((size_t)NN * NH * 4);
  us* supb    = (us*)alloc((size_t)NN * NH * 2);
  us* hb      = (us*)alloc((size_t)NN * NH * 2);
  us* hTb     = (us*)alloc((size_t)NN * NH * 2);
  us* convWT  = (us*)alloc((size_t)7 * NH * NH * 2);
  us* gatWT   = (us*)alloc((size_t)NH * NH * 2);
  us* W1t     = (us*)alloc((size_t)64 * NH * 2);
  float* va1 = (float*)alloc(NH * 4);
  float* va2 = (float*)alloc(NH * 4);
  float* fv  = (float*)alloc(NN * 4);
  float* gv  = (float*)alloc(NN * 4);
  float* Mr  = (float*)alloc(NN * 4);
  float* Lr  = (float*)alloc(NN * 4);

  float th[7];
  for (int l = 0; l < 7; ++l) {
    float t = logf(1.5f / (float)(l + 1) + 1.f);
    th[l] = t < 1.f ? t : 1.f;
  }
  float th9 = logf(1.5f / 9.f + 1.f);

  f32_to_bf16_vec<<<(NN * (long)NN) / (4 * 256), 256, 0, stream>>>(dist, distb);
  for (int i = 0; i < 7; ++i)
    transpose_f32_bf16<<<dim3(32, 32), 256, 0, stream>>>(
        conv_W + (size_t)i * NH * NH, convWT + (size_t)i * NH * NH, NH, NH);
  transpose_f32_bf16<<<dim3(32, 32), 256, 0, stream>>>(gat_W, gatWT, NH, NH);
  transpose_f32_bf16<<<dim3(2, 32), 256, 0, stream>>>(cls1_W, W1t, NH, 64);

  fc_kernel<<<NN, 256, 0, stream>>>(x, fc_W, fc_b, h0f, hf);
  transpose_f32_bf16<<<dim3(NH / 32, NN / 32), 256, 0, stream>>>(hf, hTb, NN, NH);

  for (int l = 0; l < 7; ++l) {
    gemm_db<0><<<512, 256, 0, stream>>>(distb, hTb, NN, h0f, supf, supb, nullptr, 0.f);
    gemm_db<1><<<512, 256, 0, stream>>>(supb, convWT + (size_t)l * NH * NH, NH,
                                        supf, hf, nullptr, hTb, th[l]);
  }

  wv_kernel<<<NH, 256, 0, stream>>>(gat_W, gat_a, va1, va2);
  fg_kernel<<<NN, 256, 0, stream>>>(hf, va1, va2, fv, gv);
  attn_ml<<<NN, 256, 0, stream>>>(adj, fv, gv, Mr, Lr);
  attn_p<<<(NN * (long)NN) / (4 * 256), 256, 0, stream>>>(adj, fv, gv, Mr, Lr, distb);

  gemm_db<0><<<512, 256, 0, stream>>>(distb, hTb, NN, h0f, supf, supb, nullptr, 0.f);
  gemm_db<2><<<512, 256, 0, stream>>>(supb, gatWT, NH, supf, hf, hb, nullptr, th9);

  cls_gemm<<<64, 256, 0, stream>>>(hb, W1t, cls1_b, cls3_W, cls3_b, out);
}